// Round 1
// baseline (1188.686 us; speedup 1.0000x reference)
//
#include <hip/hip_runtime.h>
#include <hip/hip_bf16.h>
#include <stdint.h>

typedef int v4i __attribute__((ext_vector_type(4)));

#define DEVI static __device__ __forceinline__

DEVI void gload16(const void* g, void* l) {
    __builtin_amdgcn_global_load_lds(
        (const __attribute__((address_space(1))) void*)g,
        (__attribute__((address_space(3))) void*)l,
        16, 0, 0);
}

// ---------------------------------------------------------------------------
// Prep: elementwise binarize fp32 -> int8 (+1 / -1), 16 elems per thread
// ---------------------------------------------------------------------------
__global__ __launch_bounds__(256) void k_bin_f32_to_i8(
    const float* __restrict__ w, int8_t* __restrict__ o, int n16)
{
    int t = blockIdx.x * 256 + threadIdx.x;
    if (t >= n16) return;
    const float4* s = (const float4*)w + (size_t)t * 4;
    union { int4 v; int8_t b[16]; } u;
#pragma unroll
    for (int i = 0; i < 4; ++i) {
        float4 f = s[i];
        u.b[i*4+0] = (f.x >= 0.f) ? (int8_t)1 : (int8_t)-1;
        u.b[i*4+1] = (f.y >= 0.f) ? (int8_t)1 : (int8_t)-1;
        u.b[i*4+2] = (f.z >= 0.f) ? (int8_t)1 : (int8_t)-1;
        u.b[i*4+3] = (f.w >= 0.f) ? (int8_t)1 : (int8_t)-1;
    }
    *(int4*)(o + (size_t)t * 16) = u.v;
}

// x [16384,784] fp32 -> A0 [16384,768] int8 (first 768 cols binarized)
__global__ __launch_bounds__(256) void k_bin_x(
    const float* __restrict__ x, int8_t* __restrict__ o)
{
    int t = blockIdx.x * 256 + threadIdx.x; // 16384*48 threads
    int row = t / 48;
    int ch  = t % 48;             // 16-col chunk
    const float4* s = (const float4*)(x + (size_t)row * 784 + ch * 16);
    union { int4 v; int8_t b[16]; } u;
#pragma unroll
    for (int i = 0; i < 4; ++i) {
        float4 f = s[i];
        u.b[i*4+0] = (f.x >= 0.f) ? (int8_t)1 : (int8_t)-1;
        u.b[i*4+1] = (f.y >= 0.f) ? (int8_t)1 : (int8_t)-1;
        u.b[i*4+2] = (f.z >= 0.f) ? (int8_t)1 : (int8_t)-1;
        u.b[i*4+3] = (f.w >= 0.f) ? (int8_t)1 : (int8_t)-1;
    }
    *(int4*)(o + (size_t)row * 768 + ch * 16) = u.v;
}

// ---------------------------------------------------------------------------
// Binary GEMM: C[M,N](int16) = A[M,K](i8 +/-1) @ B[N,K](i8 +/-1)^T
// 128x128 tile, BK=64, 4 waves (2x2), mfma_i32_16x16x64_i8, double-buffered
// LDS with global_load_lds(16B). XOR-swizzled LDS layout via pre-swizzled
// global source (linear LDS dest, rule 21).
// ---------------------------------------------------------------------------
__global__ __launch_bounds__(256, 2)
void k_gemm_bin(const int8_t* __restrict__ A, const int8_t* __restrict__ B,
                int16_t* __restrict__ C, int N, int K)
{
    __shared__ __align__(16) int8_t As[2][128 * 64];
    __shared__ __align__(16) int8_t Bs[2][128 * 64];

    const int tid  = threadIdx.x;
    const int lane = tid & 63;
    const int wave = tid >> 6;
    const int bx = blockIdx.x, by = blockIdx.y;
    const int NT = K >> 6;

    // staging: thread t covers LDS bytes t*16 of each 64-row half.
    // linear LDS (r,s): r = half*64 + (t>>2), s = t&3 (16B slot).
    // source column pre-swizzled so reads can XOR-deswizzle.
    const int sr  = tid >> 2;
    const int ss  = tid & 3;
    const int swz = ((ss ^ (sr & 3)) << 4);
    const int8_t* gA0 = A + (size_t)(by * 128 + sr)      * K + swz;
    const int8_t* gA1 = A + (size_t)(by * 128 + 64 + sr) * K + swz;
    const int8_t* gB0 = B + (size_t)(bx * 128 + sr)      * K + swz;
    const int8_t* gB1 = B + (size_t)(bx * 128 + 64 + sr) * K + swz;
    int8_t* lA = &As[0][0] + wave * 1024;   // wave-uniform base; lane lands +l*16
    int8_t* lB = &Bs[0][0] + wave * 1024;

    // fragment decode: A[row=lane&15][k=(lane>>4)*16+j], same for B (row = N-col)
    const int lrow = lane & 15;
    const int ksl  = lane >> 4;
    const int wr   = (wave >> 1) * 64;
    const int wc   = (wave & 1) * 64;
    const int fsw  = ((ksl ^ (lrow & 3)) << 4);
    int aoff[4], boff[4];
#pragma unroll
    for (int m = 0; m < 4; ++m) aoff[m] = (wr + m * 16 + lrow) * 64 + fsw;
#pragma unroll
    for (int n = 0; n < 4; ++n) boff[n] = (wc + n * 16 + lrow) * 64 + fsw;

    v4i acc[4][4];
    v4i zero = {0, 0, 0, 0};
#pragma unroll
    for (int m = 0; m < 4; ++m)
#pragma unroll
        for (int n = 0; n < 4; ++n) acc[m][n] = zero;

    // prologue: stage tile 0 into buffer 0
    gload16(gA0, lA);
    gload16(gA1, lA + 4096);
    gload16(gB0, lB);
    gload16(gB1, lB + 4096);

    for (int kt = 0; kt < NT; ++kt) {
        __syncthreads();              // compiler drains vmcnt+lgkmcnt here
        const int cur = kt & 1;
        if (kt + 1 < NT) {
            const int koff = (kt + 1) << 6;
            const int nb = (cur ^ 1) * 8192;
            gload16(gA0 + koff, lA + nb);
            gload16(gA1 + koff, lA + nb + 4096);
            gload16(gB0 + koff, lB + nb);
            gload16(gB1 + koff, lB + nb + 4096);
        }
        const int8_t* ab = &As[cur][0];
        const int8_t* bb = &Bs[cur][0];
        v4i af[4], bf[4];
#pragma unroll
        for (int m = 0; m < 4; ++m) af[m] = *(const v4i*)(ab + aoff[m]);
#pragma unroll
        for (int n = 0; n < 4; ++n) bf[n] = *(const v4i*)(bb + boff[n]);
#pragma unroll
        for (int m = 0; m < 4; ++m)
#pragma unroll
            for (int n = 0; n < 4; ++n)
                acc[m][n] = __builtin_amdgcn_mfma_i32_16x16x64_i8(
                    af[m], bf[n], acc[m][n], 0, 0, 0);
    }

    // epilogue: D[row=(lane>>4)*4+reg][col=lane&15] per 16x16 fragment
    const size_t crow0 = (size_t)(by * 128 + wr + ksl * 4);
    const int    gcol0 = bx * 128 + wc + lrow;
#pragma unroll
    for (int m = 0; m < 4; ++m)
#pragma unroll
        for (int rr = 0; rr < 4; ++rr) {
            int16_t* dst = C + (crow0 + m * 16 + rr) * N + gcol0;
#pragma unroll
            for (int n = 0; n < 4; ++n)
                dst[n * 16] = (int16_t)acc[m][n][rr];
        }
}

// ---------------------------------------------------------------------------
// Column stats: sum (int32) and sumsq (int64) per column, exact integer.
// block = 64 cols x 4 row-lanes; grid (ncols/64, 16); rows/thread = rows/64.
// ---------------------------------------------------------------------------
__global__ __launch_bounds__(256)
void k_colstats(const int16_t* __restrict__ C, int rows, int ncols,
                int* __restrict__ gsum, unsigned long long* __restrict__ gsq)
{
    const int tx = threadIdx.x & 63, ty = threadIdx.x >> 6;
    const int col = blockIdx.x * 64 + tx;
    const int rpt = rows / (gridDim.y * 4);
    const int r0  = (blockIdx.y * 4 + ty) * rpt;
    int s = 0; long long q = 0;
    for (int i = 0; i < rpt; ++i) {
        int v = C[(size_t)(r0 + i) * ncols + col];
        s += v;
        q += (long long)(v * v);
    }
    __shared__ int       ssum[4][64];
    __shared__ long long ssq[4][64];
    ssum[ty][tx] = s; ssq[ty][tx] = q;
    __syncthreads();
    if (ty == 0) {
#pragma unroll
        for (int t = 1; t < 4; ++t) { s += ssum[t][tx]; q += ssq[t][tx]; }
        atomicAdd(&gsum[col], s);
        atomicAdd(&gsq[col], (unsigned long long)q);
    }
}

// bn fold: pa = rsqrt(var+eps)*gamma ; pb = beta - mu*rsqrt*gamma
__global__ __launch_bounds__(128)
void k_finalize(const int* __restrict__ gsum, const unsigned long long* __restrict__ gsq,
                const float* __restrict__ gamma, const float* __restrict__ beta,
                float* __restrict__ pa, float* __restrict__ pb,
                int rows, int ncols_act, int ncols_pad)
{
    int c = blockIdx.x * 128 + threadIdx.x;
    if (c >= ncols_pad) return;
    double mu  = (double)gsum[c] / (double)rows;
    double var = (double)(long long)gsq[c] / (double)rows - mu * mu;
    float rs = rsqrtf((float)var + 1e-5f);
    float g  = (c < ncols_act) ? gamma[c] : 0.f;
    float be = (c < ncols_act) ? beta[c]  : 0.f;
    pa[c] = rs * g;
    pb[c] = be - (float)mu * rs * g;
}

// bn + binarize: A_next = sign(C*pa + pb), 16 elems/thread
__global__ __launch_bounds__(256)
void k_bnbin(const int16_t* __restrict__ C, const float* __restrict__ pa,
             const float* __restrict__ pb, int8_t* __restrict__ Aout,
             int n16, int colmask)
{
    int t = blockIdx.x * 256 + threadIdx.x;
    if (t >= n16) return;
    const size_t base = (size_t)t * 16;
    const int c0 = (int)(base & (size_t)colmask);
    union { int4 v; short s[8]; } u0, u1;
    u0.v = *(const int4*)(C + base);
    u1.v = *(const int4*)(C + base + 8);
    union { int4 v; int8_t b[16]; } o;
#pragma unroll
    for (int i = 0; i < 16; ++i) {
        float y = (float)((i < 8) ? u0.s[i] : u1.s[i - 8]);
        float v = y * pa[c0 + i] + pb[c0 + i];
        o.b[i] = (v >= 0.f) ? (int8_t)1 : (int8_t)-1;
    }
    *(int4*)(Aout + base) = o.v;
}

// final: bn4 + log_softmax over 10 classes, one row per thread
__global__ __launch_bounds__(256)
void k_logsoftmax(const int16_t* __restrict__ C4, const float* __restrict__ pa,
                  const float* __restrict__ pb, float* __restrict__ out, int rows)
{
    int r = blockIdx.x * 256 + threadIdx.x;
    if (r >= rows) return;
    const int16_t* row = C4 + (size_t)r * 128;
    float v[10];
    float m = -1e30f;
#pragma unroll
    for (int c = 0; c < 10; ++c) {
        v[c] = (float)row[c] * pa[c] + pb[c];
        m = fmaxf(m, v[c]);
    }
    float s = 0.f;
#pragma unroll
    for (int c = 0; c < 10; ++c) s += expf(v[c] - m);
    float ls = logf(s);
#pragma unroll
    for (int c = 0; c < 10; ++c) out[(size_t)r * 10 + c] = v[c] - m - ls;
}

// ---------------------------------------------------------------------------
extern "C" void kernel_launch(void* const* d_in, const int* in_sizes, int n_in,
                              void* d_out, int out_size, void* d_ws, size_t ws_size,
                              hipStream_t stream)
{
    (void)in_sizes; (void)n_in; (void)out_size; (void)ws_size;
    const float* x  = (const float*)d_in[0];
    const float* w1 = (const float*)d_in[1];
    const float* w2 = (const float*)d_in[2];
    const float* w3 = (const float*)d_in[3];
    const float* w4 = (const float*)d_in[4];
    const float* g1 = (const float*)d_in[5];
    const float* b1 = (const float*)d_in[6];
    const float* g2 = (const float*)d_in[7];
    const float* b2 = (const float*)d_in[8];
    const float* g3 = (const float*)d_in[9];
    const float* b3 = (const float*)d_in[10];
    const float* g4 = (const float*)d_in[11];
    const float* b4 = (const float*)d_in[12];
    float* out = (float*)d_out;

    const int B = 16384, HID = 4096, IND = 768;

    char* p = (char*)d_ws;
    size_t off = 0;
    auto alloc = [&](size_t sz) -> char* {
        char* r = p + off;
        off += (sz + 255) & ~(size_t)255;
        return r;
    };
    int8_t*  W1   = (int8_t*)alloc((size_t)HID * IND);       //  3.1 MB
    int8_t*  W2   = (int8_t*)alloc((size_t)HID * HID);       // 16.8 MB
    int8_t*  W3   = (int8_t*)alloc((size_t)HID * HID);       // 16.8 MB
    int8_t*  W4p  = (int8_t*)alloc((size_t)128 * HID);       //  0.5 MB (padded N=128)
    int8_t*  Abuf = (int8_t*)alloc((size_t)B * HID);         // 67.1 MB (A0 aliases, stride 768)
    int16_t* C    = (int16_t*)alloc((size_t)B * HID * 2);    //134.2 MB
    int16_t* C4   = (int16_t*)alloc((size_t)B * 128 * 2);    //  4.2 MB
    int*     gsum = (int*)alloc((size_t)HID * 4);
    unsigned long long* gsq = (unsigned long long*)alloc((size_t)HID * 8);
    float*   pa   = (float*)alloc((size_t)HID * 4);
    float*   pb   = (float*)alloc((size_t)HID * 4);

    // ---- prep: binarize weights + input ----
    hipMemsetAsync(W4p, 0, (size_t)128 * HID, stream);  // pad rows 10..127 = 0
    k_bin_f32_to_i8<<<(HID * IND / 16 + 255) / 256, 256, 0, stream>>>(w1, W1, HID * IND / 16);
    k_bin_f32_to_i8<<<(HID * HID / 16 + 255) / 256, 256, 0, stream>>>(w2, W2, HID * HID / 16);
    k_bin_f32_to_i8<<<(HID * HID / 16 + 255) / 256, 256, 0, stream>>>(w3, W3, HID * HID / 16);
    k_bin_f32_to_i8<<<(10 * HID / 16 + 255) / 256, 256, 0, stream>>>(w4, W4p, 10 * HID / 16);
    k_bin_x<<<B * 48 / 256, 256, 0, stream>>>(x, Abuf);   // A0 = [B,768] i8 in Abuf

    // ---- layer 1: [B,768] x [4096,768]^T ----
    k_gemm_bin<<<dim3(HID / 128, B / 128), 256, 0, stream>>>(Abuf, W1, C, HID, IND);
    hipMemsetAsync(gsum, 0, HID * 4 + HID * 8, stream);
    k_colstats<<<dim3(HID / 64, 16), 256, 0, stream>>>(C, B, HID, gsum, gsq);
    k_finalize<<<HID / 128, 128, 0, stream>>>(gsum, gsq, g1, b1, pa, pb, B, HID, HID);
    k_bnbin<<<B * HID / 16 / 256, 256, 0, stream>>>(C, pa, pb, Abuf, B * HID / 16, HID - 1);

    // ---- layer 2 ----
    k_gemm_bin<<<dim3(HID / 128, B / 128), 256, 0, stream>>>(Abuf, W2, C, HID, HID);
    hipMemsetAsync(gsum, 0, HID * 4 + HID * 8, stream);
    k_colstats<<<dim3(HID / 64, 16), 256, 0, stream>>>(C, B, HID, gsum, gsq);
    k_finalize<<<HID / 128, 128, 0, stream>>>(gsum, gsq, g2, b2, pa, pb, B, HID, HID);
    k_bnbin<<<B * HID / 16 / 256, 256, 0, stream>>>(C, pa, pb, Abuf, B * HID / 16, HID - 1);

    // ---- layer 3 ----
    k_gemm_bin<<<dim3(HID / 128, B / 128), 256, 0, stream>>>(Abuf, W3, C, HID, HID);
    hipMemsetAsync(gsum, 0, HID * 4 + HID * 8, stream);
    k_colstats<<<dim3(HID / 64, 16), 256, 0, stream>>>(C, B, HID, gsum, gsq);
    k_finalize<<<HID / 128, 128, 0, stream>>>(gsum, gsq, g3, b3, pa, pb, B, HID, HID);
    k_bnbin<<<B * HID / 16 / 256, 256, 0, stream>>>(C, pa, pb, Abuf, B * HID / 16, HID - 1);

    // ---- layer 4: N padded to 128 ----
    k_gemm_bin<<<dim3(1, B / 128), 256, 0, stream>>>(Abuf, W4p, C4, 128, HID);
    hipMemsetAsync(gsum, 0, HID * 4 + HID * 8, stream);
    k_colstats<<<dim3(2, 16), 256, 0, stream>>>(C4, B, 128, gsum, gsq);
    k_finalize<<<1, 128, 0, stream>>>(gsum, gsq, g4, b4, pa, pb, B, 10, 128);
    k_logsoftmax<<<B / 256, 256, 0, stream>>>(C4, pa, pb, out, B);
}

// Round 2
// 835.334 us; speedup vs baseline: 1.4230x; 1.4230x over previous
//
#include <hip/hip_runtime.h>
#include <hip/hip_bf16.h>
#include <stdint.h>

typedef int v4i __attribute__((ext_vector_type(4)));

#define DEVI static __device__ __forceinline__

DEVI void gload16(const void* g, void* l) {
    __builtin_amdgcn_global_load_lds(
        (const __attribute__((address_space(1))) void*)g,
        (__attribute__((address_space(3))) void*)l,
        16, 0, 0);
}

#define WAITV(n) asm volatile("s_waitcnt vmcnt(" #n ")" ::: "memory")
#define WAITL0() asm volatile("s_waitcnt lgkmcnt(0)" ::: "memory")
#define SBAR()   __builtin_amdgcn_s_barrier()
#define SCHEDB() __builtin_amdgcn_sched_barrier(0)

// ---------------------------------------------------------------------------
// Prep: elementwise binarize fp32 -> int8 (+1 / -1), 16 elems per thread
// ---------------------------------------------------------------------------
__global__ __launch_bounds__(256) void k_bin_f32_to_i8(
    const float* __restrict__ w, int8_t* __restrict__ o, int n16)
{
    int t = blockIdx.x * 256 + threadIdx.x;
    if (t >= n16) return;
    const float4* s = (const float4*)w + (size_t)t * 4;
    union { int4 v; int8_t b[16]; } u;
#pragma unroll
    for (int i = 0; i < 4; ++i) {
        float4 f = s[i];
        u.b[i*4+0] = (f.x >= 0.f) ? (int8_t)1 : (int8_t)-1;
        u.b[i*4+1] = (f.y >= 0.f) ? (int8_t)1 : (int8_t)-1;
        u.b[i*4+2] = (f.z >= 0.f) ? (int8_t)1 : (int8_t)-1;
        u.b[i*4+3] = (f.w >= 0.f) ? (int8_t)1 : (int8_t)-1;
    }
    *(int4*)(o + (size_t)t * 16) = u.v;
}

// x [16384,784] fp32 -> A0 [16384,768] int8 (first 768 cols binarized)
__global__ __launch_bounds__(256) void k_bin_x(
    const float* __restrict__ x, int8_t* __restrict__ o)
{
    int t = blockIdx.x * 256 + threadIdx.x;
    int row = t / 48;
    int ch  = t % 48;
    const float4* s = (const float4*)(x + (size_t)row * 784 + ch * 16);
    union { int4 v; int8_t b[16]; } u;
#pragma unroll
    for (int i = 0; i < 4; ++i) {
        float4 f = s[i];
        u.b[i*4+0] = (f.x >= 0.f) ? (int8_t)1 : (int8_t)-1;
        u.b[i*4+1] = (f.y >= 0.f) ? (int8_t)1 : (int8_t)-1;
        u.b[i*4+2] = (f.z >= 0.f) ? (int8_t)1 : (int8_t)-1;
        u.b[i*4+3] = (f.w >= 0.f) ? (int8_t)1 : (int8_t)-1;
    }
    *(int4*)(o + (size_t)row * 768 + ch * 16) = u.v;
}

// ---------------------------------------------------------------------------
// Binary GEMM, 256x256 tile, 8 waves (2Mx4N), BK=64B, 4-deep LDS ring,
// counted vmcnt (T4), raw s_barrier (T3), setprio (T5), row-XOR swizzle (T2),
// XCD-bijective block swizzle (T1). Fused exact column stats in epilogue.
// C[M,N](i16) = A[M,K] @ B[N,K]^T, values +/-1 as int8.
// ---------------------------------------------------------------------------
__global__ __launch_bounds__(512, 2)
void k_gemm256(const int8_t* __restrict__ A, const int8_t* __restrict__ B,
               int16_t* __restrict__ C, int* __restrict__ gsum,
               unsigned long long* __restrict__ gsq,
               int N, int K, int nbx)
{
    __shared__ __align__(16) int8_t lds[131072]; // A ring: 4x16KB, B ring: 4x16KB

    const int tid  = threadIdx.x;
    const int lane = tid & 63;
    const int wave = tid >> 6;

    // T1: bijective XCD swizzle (gridDim.x % 8 == 0 guaranteed by launch)
    const int cpx = gridDim.x >> 3;
    const int id  = blockIdx.x;
    const int sw  = (id & 7) * cpx + (id >> 3);
    const int bx  = sw % nbx;
    const int by  = sw / nbx;

    const int NT = K >> 6;

    // staging: thread t covers LDS 16B slot (j*512+t); row=(j*512+t)>>2, p=t&3.
    // physical slot p holds logical slot p^(row&3): pre-swizzle global source.
    const int sr  = tid >> 2;
    const int asw = (((tid & 3) ^ (sr & 3)) << 4);
    const int8_t* gA0 = A + (size_t)(by * 256 + sr)       * K + asw;
    const int8_t* gA1 = A + (size_t)(by * 256 + 128 + sr) * K + asw;
    const int8_t* gB0 = B + (size_t)(bx * 256 + sr)       * K + asw;
    const int8_t* gB1 = B + (size_t)(bx * 256 + 128 + sr) * K + asw;
    const int ld0 = (wave * 64) << 4;          // wave-uniform dest (+lane*16)
    const int ld1 = (512 + wave * 64) << 4;

    // fragments: A[row=16m+lrow][k=ksl*16+j]; read with matching XOR swizzle
    const int lrow = lane & 15;
    const int ksl  = lane >> 4;
    const int wr = (wave >> 2) * 128;
    const int wc = (wave & 3) * 64;
    const int fsw = ((ksl ^ (lrow & 3)) << 4);
    int aoff[8], boff[4];
#pragma unroll
    for (int m = 0; m < 8; ++m) aoff[m] = ((wr + m * 16 + lrow) << 6) + fsw;
#pragma unroll
    for (int n = 0; n < 4; ++n) boff[n] = ((wc + n * 16 + lrow) << 6) + fsw;

    v4i acc[8][4];
    v4i zero = {0, 0, 0, 0};
#pragma unroll
    for (int m = 0; m < 8; ++m)
#pragma unroll
        for (int n = 0; n < 4; ++n) acc[m][n] = zero;

#define STAGE_A(kt, b) do { const int _o = (kt) << 6;                    \
        int8_t* _d = lds + (b) * 16384;                                  \
        gload16(gA0 + _o, _d + ld0); gload16(gA1 + _o, _d + ld1); } while (0)
#define STAGE_B(kt, b) do { const int _o = (kt) << 6;                    \
        int8_t* _d = lds + 65536 + (b) * 16384;                          \
        gload16(gB0 + _o, _d + ld0); gload16(gB1 + _o, _d + ld1); } while (0)

    // prologue: tiles 0,1,2 in flight (12 loads); drain tile 0 (leave 8)
    STAGE_A(0, 0); STAGE_B(0, 0);
    STAGE_A(1, 1); STAGE_B(1, 1);
    STAGE_A(2, 2); STAGE_B(2, 2);
    WAITV(8);
    SBAR();

    for (int kt = 0; kt < NT; ++kt) {
        const int b = kt & 3;
        const int8_t* ab = lds + b * 16384;
        const int8_t* bb = lds + 65536 + b * 16384;
        const int sb = (kt + 3) & 3;
        const bool st = (kt + 3 < NT);

        // ---- phase A: quadrant m0-3 x n0-3 ----
        v4i af[4], bf[4];
#pragma unroll
        for (int m = 0; m < 4; ++m) af[m] = *(const v4i*)(ab + aoff[m]);
#pragma unroll
        for (int n = 0; n < 4; ++n) bf[n] = *(const v4i*)(bb + boff[n]);
        if (st) STAGE_A(kt + 3, sb);
        SBAR();
        WAITL0();
        SCHEDB();
        __builtin_amdgcn_s_setprio(1);
#pragma unroll
        for (int m = 0; m < 4; ++m)
#pragma unroll
            for (int n = 0; n < 4; ++n)
                acc[m][n] = __builtin_amdgcn_mfma_i32_16x16x64_i8(
                    af[m], bf[n], acc[m][n], 0, 0, 0);
        __builtin_amdgcn_s_setprio(0);
        SBAR();

        // ---- phase B: quadrant m4-7 x n0-3 ----
        v4i ag[4];
#pragma unroll
        for (int m = 0; m < 4; ++m) ag[m] = *(const v4i*)(ab + aoff[4 + m]);
        if (st) STAGE_B(kt + 3, sb);
        // counted vmcnt: drain tile kt+1 (leave kt+2, kt+3 in flight)
        if (kt < NT - 3)       { WAITV(8); }
        else if (kt == NT - 3) { WAITV(4); }
        else if (kt == NT - 2) { WAITV(0); }
        SBAR();
        WAITL0();
        SCHEDB();
        __builtin_amdgcn_s_setprio(1);
#pragma unroll
        for (int m = 0; m < 4; ++m)
#pragma unroll
            for (int n = 0; n < 4; ++n)
                acc[4 + m][n] = __builtin_amdgcn_mfma_i32_16x16x64_i8(
                    ag[m], bf[n], acc[4 + m][n], 0, 0, 0);
        __builtin_amdgcn_s_setprio(0);
        SBAR();
    }
#undef STAGE_A
#undef STAGE_B

    // ---- epilogue: C write (i16) + fused exact column stats ----
    const int row0 = by * 256 + wr + ksl * 4;
    const int col0 = bx * 256 + wc + lrow;
#pragma unroll
    for (int m = 0; m < 8; ++m)
#pragma unroll
        for (int rr = 0; rr < 4; ++rr) {
            int16_t* dst = C + (size_t)(row0 + m * 16 + rr) * N + col0;
#pragma unroll
            for (int n = 0; n < 4; ++n)
                dst[n * 16] = (int16_t)acc[m][n][rr];
        }
#pragma unroll
    for (int n = 0; n < 4; ++n) {
        int s = 0; unsigned q = 0;
#pragma unroll
        for (int m = 0; m < 8; ++m)
#pragma unroll
            for (int rr = 0; rr < 4; ++rr) {
                int v = acc[m][n][rr];
                s += v;
                q += (unsigned)(v * v);
            }
        // reduce over the 4 ksl lane-groups (wave covers 128 rows)
        s += __shfl_xor(s, 16);
        s += __shfl_xor(s, 32);
        q += (unsigned)__shfl_xor((int)q, 16);
        q += (unsigned)__shfl_xor((int)q, 32);
        if (ksl == 0) {
            const int col = col0 + n * 16;
            atomicAdd(&gsum[col], s);
            atomicAdd(&gsq[col], (unsigned long long)q);
        }
    }
}

// ---------------------------------------------------------------------------
// Layer-4 split-K GEMM: C4[16384,16](i32, atomic) = A @ W4p[16,4096]^T
// grid (M/128, 8): 4 waves/block, 2 m-frags each, K-chunk 512. Streaming.
// ---------------------------------------------------------------------------
__global__ __launch_bounds__(256)
void k_gemm4(const int8_t* __restrict__ A, const int8_t* __restrict__ Bw,
             int* __restrict__ C4, int K)
{
    const int lane = threadIdx.x & 63;
    const int wave = threadIdx.x >> 6;
    const int lrow = lane & 15, ksl = lane >> 4;
    const int r0 = blockIdx.x * 128 + wave * 32;
    const int k0 = blockIdx.y * 512;

    const int8_t* ap0 = A + (size_t)(r0 + lrow) * K + k0 + ksl * 16;
    const int8_t* ap1 = ap0 + (size_t)16 * K;
    const int8_t* bp  = Bw + (size_t)lrow * K + k0 + ksl * 16;

    v4i acc0 = {0,0,0,0}, acc1 = {0,0,0,0};
#pragma unroll
    for (int kk = 0; kk < 8; ++kk) {
        v4i a0 = *(const v4i*)(ap0 + kk * 64);
        v4i a1 = *(const v4i*)(ap1 + kk * 64);
        v4i b  = *(const v4i*)(bp  + kk * 64);
        acc0 = __builtin_amdgcn_mfma_i32_16x16x64_i8(a0, b, acc0, 0, 0, 0);
        acc1 = __builtin_amdgcn_mfma_i32_16x16x64_i8(a1, b, acc1, 0, 0, 0);
    }
#pragma unroll
    for (int rr = 0; rr < 4; ++rr) {
        atomicAdd(&C4[(size_t)(r0 + ksl * 4 + rr) * 16 + lrow], acc0[rr]);
        atomicAdd(&C4[(size_t)(r0 + 16 + ksl * 4 + rr) * 16 + lrow], acc1[rr]);
    }
}

// stats for the 16-col (10 active) layer-4 output, int32 input
__global__ __launch_bounds__(256)
void k_colstats4(const int* __restrict__ C4, int rows,
                 int* __restrict__ gsum, unsigned long long* __restrict__ gsq)
{
    const int col = threadIdx.x & 15, grp = threadIdx.x >> 4;
    const int rpb = rows / gridDim.x;
    const int r0  = blockIdx.x * rpb;
    int s = 0; unsigned long long q = 0;
    for (int r = grp; r < rpb; r += 16) {
        int v = C4[(size_t)(r0 + r) * 16 + col];
        s += v;
        q += (unsigned long long)((long long)v * (long long)v);
    }
    __shared__ int ss[256];
    __shared__ unsigned long long sq[256];
    ss[threadIdx.x] = s; sq[threadIdx.x] = q;
    __syncthreads();
    if (grp == 0) {
#pragma unroll
        for (int t = 1; t < 16; ++t) { s += ss[t * 16 + col]; q += sq[t * 16 + col]; }
        atomicAdd(&gsum[col], s);
        atomicAdd(&gsq[col], q);
    }
}

// bn fold: pa = rsqrt(var+eps)*gamma ; pb = beta - mu*rsqrt*gamma
__global__ __launch_bounds__(128)
void k_finalize(const int* __restrict__ gsum, const unsigned long long* __restrict__ gsq,
                const float* __restrict__ gamma, const float* __restrict__ beta,
                float* __restrict__ pa, float* __restrict__ pb,
                int rows, int ncols_act, int ncols_pad)
{
    int c = blockIdx.x * 128 + threadIdx.x;
    if (c >= ncols_pad) return;
    double mu  = (double)gsum[c] / (double)rows;
    double var = (double)(long long)gsq[c] / (double)rows - mu * mu;
    float rs = rsqrtf((float)var + 1e-5f);
    float g  = (c < ncols_act) ? gamma[c] : 0.f;
    float be = (c < ncols_act) ? beta[c]  : 0.f;
    pa[c] = rs * g;
    pb[c] = be - (float)mu * rs * g;
}

// bn + binarize: A_next = sign(C*pa + pb), 16 elems/thread, vectorized pa/pb
__global__ __launch_bounds__(256)
void k_bnbin(const int16_t* __restrict__ C, const float* __restrict__ pa,
             const float* __restrict__ pb, int8_t* __restrict__ Aout,
             int n16, int colmask)
{
    int t = blockIdx.x * 256 + threadIdx.x;
    if (t >= n16) return;
    const size_t base = (size_t)t * 16;
    const int c0 = (int)(base & (size_t)colmask);
    union { int4 v; short s[8]; } u0, u1;
    u0.v = *(const int4*)(C + base);
    u1.v = *(const int4*)(C + base + 8);
    float4 a[4], b[4];
#pragma unroll
    for (int i = 0; i < 4; ++i) {
        a[i] = *(const float4*)(pa + c0 + i * 4);
        b[i] = *(const float4*)(pb + c0 + i * 4);
    }
    union { int4 v; int8_t b[16]; } o;
#pragma unroll
    for (int i = 0; i < 16; ++i) {
        float y = (float)((i < 8) ? u0.s[i] : u1.s[i - 8]);
        float aa = ((const float*)&a[i >> 2])[i & 3];
        float bb = ((const float*)&b[i >> 2])[i & 3];
        o.b[i] = (y * aa + bb >= 0.f) ? (int8_t)1 : (int8_t)-1;
    }
    *(int4*)(Aout + base) = o.v;
}

// final: bn4 + log_softmax over 10 classes (C4 int32, stride 16)
__global__ __launch_bounds__(256)
void k_logsoftmax(const int* __restrict__ C4, const float* __restrict__ pa,
                  const float* __restrict__ pb, float* __restrict__ out, int rows)
{
    int r = blockIdx.x * 256 + threadIdx.x;
    if (r >= rows) return;
    const int* row = C4 + (size_t)r * 16;
    float v[10];
    float m = -1e30f;
#pragma unroll
    for (int c = 0; c < 10; ++c) {
        v[c] = (float)row[c] * pa[c] + pb[c];
        m = fmaxf(m, v[c]);
    }
    float s = 0.f;
#pragma unroll
    for (int c = 0; c < 10; ++c) s += expf(v[c] - m);
    float ls = logf(s);
#pragma unroll
    for (int c = 0; c < 10; ++c) out[(size_t)r * 10 + c] = v[c] - m - ls;
}

// ---------------------------------------------------------------------------
extern "C" void kernel_launch(void* const* d_in, const int* in_sizes, int n_in,
                              void* d_out, int out_size, void* d_ws, size_t ws_size,
                              hipStream_t stream)
{
    (void)in_sizes; (void)n_in; (void)out_size; (void)ws_size;
    const float* x  = (const float*)d_in[0];
    const float* w1 = (const float*)d_in[1];
    const float* w2 = (const float*)d_in[2];
    const float* w3 = (const float*)d_in[3];
    const float* w4 = (const float*)d_in[4];
    const float* g1 = (const float*)d_in[5];
    const float* b1 = (const float*)d_in[6];
    const float* g2 = (const float*)d_in[7];
    const float* b2 = (const float*)d_in[8];
    const float* g3 = (const float*)d_in[9];
    const float* b3 = (const float*)d_in[10];
    const float* g4 = (const float*)d_in[11];
    const float* b4 = (const float*)d_in[12];
    float* out = (float*)d_out;

    const int B = 16384, HID = 4096, IND = 768;

    char* p = (char*)d_ws;
    size_t off = 0;
    auto alloc = [&](size_t sz) -> char* {
        char* r = p + off;
        off += (sz + 255) & ~(size_t)255;
        return r;
    };
    int8_t*  W1   = (int8_t*)alloc((size_t)HID * IND);
    int8_t*  W2   = (int8_t*)alloc((size_t)HID * HID);
    int8_t*  W3   = (int8_t*)alloc((size_t)HID * HID);
    int8_t*  W4p  = (int8_t*)alloc((size_t)16 * HID);
    int8_t*  Abuf = (int8_t*)alloc((size_t)B * HID);
    int16_t* C    = (int16_t*)alloc((size_t)B * HID * 2);
    int*     C4   = (int*)alloc((size_t)B * 16 * 4);
    int*     gsum = (int*)alloc((size_t)HID * 4);
    unsigned long long* gsq = (unsigned long long*)alloc((size_t)HID * 8);
    float*   pa   = (float*)alloc((size_t)HID * 4);
    float*   pb   = (float*)alloc((size_t)HID * 4);

    // ---- prep ----
    hipMemsetAsync(W4p, 0, (size_t)16 * HID, stream);
    k_bin_f32_to_i8<<<(HID * IND / 16 + 255) / 256, 256, 0, stream>>>(w1, W1, HID * IND / 16);
    k_bin_f32_to_i8<<<(HID * HID / 16 + 255) / 256, 256, 0, stream>>>(w2, W2, HID * HID / 16);
    k_bin_f32_to_i8<<<(HID * HID / 16 + 255) / 256, 256, 0, stream>>>(w3, W3, HID * HID / 16);
    k_bin_f32_to_i8<<<(10 * HID / 16 + 255) / 256, 256, 0, stream>>>(w4, W4p, 10 * HID / 16);
    k_bin_x<<<B * 48 / 256, 256, 0, stream>>>(x, Abuf);

    const int nbx = HID / 256, nby = B / 256;   // 16 x 64 = 1024 blocks (%8==0)

    // ---- layer 1 ----
    hipMemsetAsync(gsum, 0, HID * 12, stream);
    k_gemm256<<<nbx * nby, 512, 0, stream>>>(Abuf, W1, C, gsum, gsq, HID, IND, nbx);
    k_finalize<<<HID / 128, 128, 0, stream>>>(gsum, gsq, g1, b1, pa, pb, B, HID, HID);
    k_bnbin<<<B * HID / 16 / 256, 256, 0, stream>>>(C, pa, pb, Abuf, B * HID / 16, HID - 1);

    // ---- layer 2 ----
    hipMemsetAsync(gsum, 0, HID * 12, stream);
    k_gemm256<<<nbx * nby, 512, 0, stream>>>(Abuf, W2, C, gsum, gsq, HID, HID, nbx);
    k_finalize<<<HID / 128, 128, 0, stream>>>(gsum, gsq, g2, b2, pa, pb, B, HID, HID);
    k_bnbin<<<B * HID / 16 / 256, 256, 0, stream>>>(C, pa, pb, Abuf, B * HID / 16, HID - 1);

    // ---- layer 3 ----
    hipMemsetAsync(gsum, 0, HID * 12, stream);
    k_gemm256<<<nbx * nby, 512, 0, stream>>>(Abuf, W3, C, gsum, gsq, HID, HID, nbx);
    k_finalize<<<HID / 128, 128, 0, stream>>>(gsum, gsq, g3, b3, pa, pb, B, HID, HID);
    k_bnbin<<<B * HID / 16 / 256, 256, 0, stream>>>(C, pa, pb, Abuf, B * HID / 16, HID - 1);

    // ---- layer 4 (split-K, int32 atomics) ----
    hipMemsetAsync(C4, 0, (size_t)B * 16 * 4, stream);
    k_gemm4<<<dim3(B / 128, 8), 256, 0, stream>>>(Abuf, W4p, C4, HID);
    hipMemsetAsync(gsum, 0, HID * 12, stream);
    k_colstats4<<<16, 256, 0, stream>>>(C4, B, gsum, gsq);
    k_finalize<<<1, 128, 0, stream>>>(gsum, gsq, g4, b4, pa, pb, B, 10, 16);
    k_logsoftmax<<<B / 256, 256, 0, stream>>>(C4, pa, pb, out, B);
}

// Round 3
// 799.541 us; speedup vs baseline: 1.4867x; 1.0448x over previous
//
#include <hip/hip_runtime.h>
#include <hip/hip_bf16.h>
#include <stdint.h>

typedef int v4i __attribute__((ext_vector_type(4)));

#define DEVI static __device__ __forceinline__

DEVI void gload16(const void* g, void* l) {
    __builtin_amdgcn_global_load_lds(
        (const __attribute__((address_space(1))) void*)g,
        (__attribute__((address_space(3))) void*)l,
        16, 0, 0);
}

#define WAITV(n) asm volatile("s_waitcnt vmcnt(" #n ")" ::: "memory")
#define SBAR()   __builtin_amdgcn_s_barrier()

// ---------------------------------------------------------------------------
// Prep: elementwise binarize fp32 -> int8 (+1 / -1), 16 elems per thread
// ---------------------------------------------------------------------------
__global__ __launch_bounds__(256) void k_bin_f32_to_i8(
    const float* __restrict__ w, int8_t* __restrict__ o, int n16)
{
    int t = blockIdx.x * 256 + threadIdx.x;
    if (t >= n16) return;
    const float4* s = (const float4*)w + (size_t)t * 4;
    union { int4 v; int8_t b[16]; } u;
#pragma unroll
    for (int i = 0; i < 4; ++i) {
        float4 f = s[i];
        u.b[i*4+0] = (f.x >= 0.f) ? (int8_t)1 : (int8_t)-1;
        u.b[i*4+1] = (f.y >= 0.f) ? (int8_t)1 : (int8_t)-1;
        u.b[i*4+2] = (f.z >= 0.f) ? (int8_t)1 : (int8_t)-1;
        u.b[i*4+3] = (f.w >= 0.f) ? (int8_t)1 : (int8_t)-1;
    }
    *(int4*)(o + (size_t)t * 16) = u.v;
}

// x [16384,784] fp32 -> A0 [16384,768] int8
__global__ __launch_bounds__(256) void k_bin_x(
    const float* __restrict__ x, int8_t* __restrict__ o)
{
    int t = blockIdx.x * 256 + threadIdx.x;
    int row = t / 48;
    int ch  = t % 48;
    const float4* s = (const float4*)(x + (size_t)row * 784 + ch * 16);
    union { int4 v; int8_t b[16]; } u;
#pragma unroll
    for (int i = 0; i < 4; ++i) {
        float4 f = s[i];
        u.b[i*4+0] = (f.x >= 0.f) ? (int8_t)1 : (int8_t)-1;
        u.b[i*4+1] = (f.y >= 0.f) ? (int8_t)1 : (int8_t)-1;
        u.b[i*4+2] = (f.z >= 0.f) ? (int8_t)1 : (int8_t)-1;
        u.b[i*4+3] = (f.w >= 0.f) ? (int8_t)1 : (int8_t)-1;
    }
    *(int4*)(o + (size_t)row * 768 + ch * 16) = u.v;
}

// ---------------------------------------------------------------------------
// Binary GEMM, 256x256 tile, 8 waves (2Mx4N), BK=64B, 4-deep LDS ring.
// One s_barrier per K-tile; counted vmcnt(4) (2-tile drain margin) enables
// register prefetch of next tile's A/B fragments under current MFMA cluster.
// Swizzle: slot ^= (row>>1)&3  (bijective over row mod 8 -> conflict-free
// wave64 ds_read_b128). Fused exact column stats in epilogue.
// ---------------------------------------------------------------------------
__global__ __launch_bounds__(512, 2)
void k_gemm256(const int8_t* __restrict__ A, const int8_t* __restrict__ B,
               int16_t* __restrict__ C, int* __restrict__ gsum,
               unsigned long long* __restrict__ gsq,
               int N, int K, int nbx)
{
    __shared__ __align__(16) int8_t lds[131072]; // A ring 4x16KB | B ring 4x16KB

    const int tid  = threadIdx.x;
    const int lane = tid & 63;
    const int wave = tid >> 6;

    // T1: bijective XCD swizzle (gridDim.x % 8 == 0)
    const int cpx = gridDim.x >> 3;
    const int id  = blockIdx.x;
    const int sw  = (id & 7) * cpx + (id >> 3);
    const int bx  = sw % nbx;
    const int by  = sw / nbx;

    const int NT = K >> 6;

    // staging: thread t -> LDS row sr=t>>2, phys 16B slot ss=t&3.
    // phys slot p of row r holds logical slot p ^ ((r>>1)&3): pre-swizzle src.
    const int sr  = tid >> 2;
    const int asw = (((tid & 3) ^ ((sr >> 1) & 3)) << 4);
    const int8_t* gA0 = A + (size_t)(by * 256 + sr)       * K + asw;
    const int8_t* gA1 = A + (size_t)(by * 256 + 128 + sr) * K + asw;
    const int8_t* gB0 = B + (size_t)(bx * 256 + sr)       * K + asw;
    const int8_t* gB1 = B + (size_t)(bx * 256 + 128 + sr) * K + asw;
    const int ld0 = (wave * 64) << 4;
    const int ld1 = (512 + wave * 64) << 4;

    // fragments: logical slot ksl of row (16m+lrow) at phys ksl^((lrow>>1)&3)
    const int lrow = lane & 15;
    const int ksl  = lane >> 4;
    const int wr = (wave >> 2) * 128;
    const int wc = (wave & 3) * 64;
    const int fsw = ((ksl ^ ((lrow >> 1) & 3)) << 4);
    int aoff[8], boff[4];
#pragma unroll
    for (int m = 0; m < 8; ++m) aoff[m] = ((wr + m * 16 + lrow) << 6) + fsw;
#pragma unroll
    for (int n = 0; n < 4; ++n) boff[n] = ((wc + n * 16 + lrow) << 6) + fsw;

    v4i acc[8][4];
    v4i zero = {0, 0, 0, 0};
#pragma unroll
    for (int m = 0; m < 8; ++m)
#pragma unroll
        for (int n = 0; n < 4; ++n) acc[m][n] = zero;

#define STAGE_A(kt, b) do { const int _o = (kt) << 6;                    \
        int8_t* _d = lds + (b) * 16384;                                  \
        gload16(gA0 + _o, _d + ld0); gload16(gA1 + _o, _d + ld1); } while (0)
#define STAGE_B(kt, b) do { const int _o = (kt) << 6;                    \
        int8_t* _d = lds + 65536 + (b) * 16384;                          \
        gload16(gB0 + _o, _d + ld0); gload16(gB1 + _o, _d + ld1); } while (0)

    // prologue: tiles 0,1,2 in flight; drain 0 AND 1 (2-tile margin)
    STAGE_A(0, 0); STAGE_B(0, 0);
    STAGE_A(1, 1); STAGE_B(1, 1);
    STAGE_A(2, 2); STAGE_B(2, 2);
    WAITV(4);
    SBAR();

    v4i afC[4], bfC[4];
    {
        const int8_t* ab = lds;
        const int8_t* bb = lds + 65536;
#pragma unroll
        for (int m = 0; m < 4; ++m) afC[m] = *(const v4i*)(ab + aoff[m]);
#pragma unroll
        for (int n = 0; n < 4; ++n) bfC[n] = *(const v4i*)(bb + boff[n]);
    }

    for (int kt = 0; kt < NT - 1; ++kt) {
        const int b  = kt & 3;
        const int nb = (kt + 1) & 3;
        const int8_t* ab  = lds + b * 16384;
        const int8_t* abN = lds + nb * 16384;
        const int8_t* bbN = lds + 65536 + nb * 16384;

        if (kt + 3 < NT) { const int sb = (kt + 3) & 3; STAGE_A(kt + 3, sb); STAGE_B(kt + 3, sb); }
        if (kt < NT - 3)       { WAITV(4); }   // drain tile kt+2
        else if (kt == NT - 3) { WAITV(0); }   // drain final tile

        // rows 64..127 of current buffer (needed by MFMA-B; hidden under A)
        v4i ag[4];
#pragma unroll
        for (int m = 0; m < 4; ++m) ag[m] = *(const v4i*)(ab + aoff[4 + m]);

        __builtin_amdgcn_s_setprio(1);
#pragma unroll
        for (int m = 0; m < 4; ++m)
#pragma unroll
            for (int n = 0; n < 4; ++n)
                acc[m][n] = __builtin_amdgcn_mfma_i32_16x16x64_i8(
                    afC[m], bfC[n], acc[m][n], 0, 0, 0);
        __builtin_amdgcn_s_setprio(0);

        // prefetch next tile's fragments (buffer kt+1 drained @ tile kt-1)
        v4i afN[4], bfN[4];
#pragma unroll
        for (int m = 0; m < 4; ++m) afN[m] = *(const v4i*)(abN + aoff[m]);
#pragma unroll
        for (int n = 0; n < 4; ++n) bfN[n] = *(const v4i*)(bbN + boff[n]);

        __builtin_amdgcn_s_setprio(1);
#pragma unroll
        for (int m = 0; m < 4; ++m)
#pragma unroll
            for (int n = 0; n < 4; ++n)
                acc[4 + m][n] = __builtin_amdgcn_mfma_i32_16x16x64_i8(
                    ag[m], bfC[n], acc[4 + m][n], 0, 0, 0);
        __builtin_amdgcn_s_setprio(0);

        SBAR();
#pragma unroll
        for (int m = 0; m < 4; ++m) afC[m] = afN[m];
#pragma unroll
        for (int n = 0; n < 4; ++n) bfC[n] = bfN[n];
    }

    // last tile (no prefetch, no stage)
    {
        const int8_t* ab = lds + ((NT - 1) & 3) * 16384;
        v4i ag[4];
#pragma unroll
        for (int m = 0; m < 4; ++m) ag[m] = *(const v4i*)(ab + aoff[4 + m]);
        __builtin_amdgcn_s_setprio(1);
#pragma unroll
        for (int m = 0; m < 4; ++m)
#pragma unroll
            for (int n = 0; n < 4; ++n)
                acc[m][n] = __builtin_amdgcn_mfma_i32_16x16x64_i8(
                    afC[m], bfC[n], acc[m][n], 0, 0, 0);
#pragma unroll
        for (int m = 0; m < 4; ++m)
#pragma unroll
            for (int n = 0; n < 4; ++n)
                acc[4 + m][n] = __builtin_amdgcn_mfma_i32_16x16x64_i8(
                    ag[m], bfC[n], acc[4 + m][n], 0, 0, 0);
        __builtin_amdgcn_s_setprio(0);
    }
#undef STAGE_A
#undef STAGE_B

    // ---- epilogue: C write (i16) + fused exact column stats ----
    const int row0 = by * 256 + wr + ksl * 4;
    const int col0 = bx * 256 + wc + lrow;
#pragma unroll
    for (int m = 0; m < 8; ++m)
#pragma unroll
        for (int rr = 0; rr < 4; ++rr) {
            int16_t* dst = C + (size_t)(row0 + m * 16 + rr) * N + col0;
#pragma unroll
            for (int n = 0; n < 4; ++n)
                dst[n * 16] = (int16_t)acc[m][n][rr];
        }
#pragma unroll
    for (int n = 0; n < 4; ++n) {
        int s = 0; unsigned q = 0;
#pragma unroll
        for (int m = 0; m < 8; ++m)
#pragma unroll
            for (int rr = 0; rr < 4; ++rr) {
                int v = acc[m][n][rr];
                s += v;
                q += (unsigned)(v * v);
            }
        s += __shfl_xor(s, 16);
        s += __shfl_xor(s, 32);
        q += (unsigned)__shfl_xor((int)q, 16);
        q += (unsigned)__shfl_xor((int)q, 32);
        if (ksl == 0) {
            const int col = col0 + n * 16;
            atomicAdd(&gsum[col], s);
            atomicAdd(&gsq[col], (unsigned long long)q);
        }
    }
}

// ---------------------------------------------------------------------------
// Layer-4 split-K GEMM: C4[16384,16](i32, atomic) = A @ W4p[16,4096]^T
// ---------------------------------------------------------------------------
__global__ __launch_bounds__(256)
void k_gemm4(const int8_t* __restrict__ A, const int8_t* __restrict__ Bw,
             int* __restrict__ C4, int K)
{
    const int lane = threadIdx.x & 63;
    const int wave = threadIdx.x >> 6;
    const int lrow = lane & 15, ksl = lane >> 4;
    const int r0 = blockIdx.x * 128 + wave * 32;
    const int k0 = blockIdx.y * 512;

    const int8_t* ap0 = A + (size_t)(r0 + lrow) * K + k0 + ksl * 16;
    const int8_t* ap1 = ap0 + (size_t)16 * K;
    const int8_t* bp  = Bw + (size_t)lrow * K + k0 + ksl * 16;

    v4i acc0 = {0,0,0,0}, acc1 = {0,0,0,0};
#pragma unroll
    for (int kk = 0; kk < 8; ++kk) {
        v4i a0 = *(const v4i*)(ap0 + kk * 64);
        v4i a1 = *(const v4i*)(ap1 + kk * 64);
        v4i b  = *(const v4i*)(bp  + kk * 64);
        acc0 = __builtin_amdgcn_mfma_i32_16x16x64_i8(a0, b, acc0, 0, 0, 0);
        acc1 = __builtin_amdgcn_mfma_i32_16x16x64_i8(a1, b, acc1, 0, 0, 0);
    }
#pragma unroll
    for (int rr = 0; rr < 4; ++rr) {
        atomicAdd(&C4[(size_t)(r0 + ksl * 4 + rr) * 16 + lrow], acc0[rr]);
        atomicAdd(&C4[(size_t)(r0 + 16 + ksl * 4 + rr) * 16 + lrow], acc1[rr]);
    }
}

// stats for the 16-col (10 active) layer-4 output, int32 input
__global__ __launch_bounds__(256)
void k_colstats4(const int* __restrict__ C4, int rows,
                 int* __restrict__ gsum, unsigned long long* __restrict__ gsq)
{
    const int col = threadIdx.x & 15, grp = threadIdx.x >> 4;
    const int rpb = rows / gridDim.x;
    const int r0  = blockIdx.x * rpb;
    int s = 0; unsigned long long q = 0;
    for (int r = grp; r < rpb; r += 16) {
        int v = C4[(size_t)(r0 + r) * 16 + col];
        s += v;
        q += (unsigned long long)((long long)v * (long long)v);
    }
    __shared__ int ss[256];
    __shared__ unsigned long long sq[256];
    ss[threadIdx.x] = s; sq[threadIdx.x] = q;
    __syncthreads();
    if (grp == 0) {
#pragma unroll
        for (int t = 1; t < 16; ++t) { s += ss[t * 16 + col]; q += sq[t * 16 + col]; }
        atomicAdd(&gsum[col], s);
        atomicAdd(&gsq[col], q);
    }
}

// bn fold: pa = rsqrt(var+eps)*gamma ; pb = beta - mu*rsqrt*gamma
__global__ __launch_bounds__(128)
void k_finalize(const int* __restrict__ gsum, const unsigned long long* __restrict__ gsq,
                const float* __restrict__ gamma, const float* __restrict__ beta,
                float* __restrict__ pa, float* __restrict__ pb,
                int rows, int ncols_act, int ncols_pad)
{
    int c = blockIdx.x * 128 + threadIdx.x;
    if (c >= ncols_pad) return;
    double mu  = (double)gsum[c] / (double)rows;
    double var = (double)(long long)gsq[c] / (double)rows - mu * mu;
    float rs = rsqrtf((float)var + 1e-5f);
    float g  = (c < ncols_act) ? gamma[c] : 0.f;
    float be = (c < ncols_act) ? beta[c]  : 0.f;
    pa[c] = rs * g;
    pb[c] = be - (float)mu * rs * g;
}

// bn + binarize: A_next = sign(C*pa + pb), 16 elems/thread
__global__ __launch_bounds__(256)
void k_bnbin(const int16_t* __restrict__ C, const float* __restrict__ pa,
             const float* __restrict__ pb, int8_t* __restrict__ Aout,
             int n16, int colmask)
{
    int t = blockIdx.x * 256 + threadIdx.x;
    if (t >= n16) return;
    const size_t base = (size_t)t * 16;
    const int c0 = (int)(base & (size_t)colmask);
    union { int4 v; short s[8]; } u0, u1;
    u0.v = *(const int4*)(C + base);
    u1.v = *(const int4*)(C + base + 8);
    float4 a[4], b[4];
#pragma unroll
    for (int i = 0; i < 4; ++i) {
        a[i] = *(const float4*)(pa + c0 + i * 4);
        b[i] = *(const float4*)(pb + c0 + i * 4);
    }
    union { int4 v; int8_t b[16]; } o;
#pragma unroll
    for (int i = 0; i < 16; ++i) {
        float y = (float)((i < 8) ? u0.s[i] : u1.s[i - 8]);
        float aa = ((const float*)&a[i >> 2])[i & 3];
        float bb = ((const float*)&b[i >> 2])[i & 3];
        o.b[i] = (y * aa + bb >= 0.f) ? (int8_t)1 : (int8_t)-1;
    }
    *(int4*)(Aout + base) = o.v;
}

// final: bn4 + log_softmax over 10 classes (C4 int32, stride 16)
__global__ __launch_bounds__(256)
void k_logsoftmax(const int* __restrict__ C4, const float* __restrict__ pa,
                  const float* __restrict__ pb, float* __restrict__ out, int rows)
{
    int r = blockIdx.x * 256 + threadIdx.x;
    if (r >= rows) return;
    const int* row = C4 + (size_t)r * 16;
    float v[10];
    float m = -1e30f;
#pragma unroll
    for (int c = 0; c < 10; ++c) {
        v[c] = (float)row[c] * pa[c] + pb[c];
        m = fmaxf(m, v[c]);
    }
    float s = 0.f;
#pragma unroll
    for (int c = 0; c < 10; ++c) s += expf(v[c] - m);
    float ls = logf(s);
#pragma unroll
    for (int c = 0; c < 10; ++c) out[(size_t)r * 10 + c] = v[c] - m - ls;
}

// ---------------------------------------------------------------------------
extern "C" void kernel_launch(void* const* d_in, const int* in_sizes, int n_in,
                              void* d_out, int out_size, void* d_ws, size_t ws_size,
                              hipStream_t stream)
{
    (void)in_sizes; (void)n_in; (void)out_size; (void)ws_size;
    const float* x  = (const float*)d_in[0];
    const float* w1 = (const float*)d_in[1];
    const float* w2 = (const float*)d_in[2];
    const float* w3 = (const float*)d_in[3];
    const float* w4 = (const float*)d_in[4];
    const float* g1 = (const float*)d_in[5];
    const float* b1 = (const float*)d_in[6];
    const float* g2 = (const float*)d_in[7];
    const float* b2 = (const float*)d_in[8];
    const float* g3 = (const float*)d_in[9];
    const float* b3 = (const float*)d_in[10];
    const float* g4 = (const float*)d_in[11];
    const float* b4 = (const float*)d_in[12];
    float* out = (float*)d_out;

    const int B = 16384, HID = 4096, IND = 768;

    char* p = (char*)d_ws;
    size_t off = 0;
    auto alloc = [&](size_t sz) -> char* {
        char* r = p + off;
        off += (sz + 255) & ~(size_t)255;
        return r;
    };
    int8_t*  W1   = (int8_t*)alloc((size_t)HID * IND);
    int8_t*  W2   = (int8_t*)alloc((size_t)HID * HID);
    int8_t*  W3   = (int8_t*)alloc((size_t)HID * HID);
    int8_t*  W4p  = (int8_t*)alloc((size_t)16 * HID);
    int8_t*  Abuf = (int8_t*)alloc((size_t)B * HID);
    int16_t* C    = (int16_t*)alloc((size_t)B * HID * 2);
    int*     C4   = (int*)alloc((size_t)B * 16 * 4);
    int*     gsum = (int*)alloc((size_t)HID * 4);
    unsigned long long* gsq = (unsigned long long*)alloc((size_t)HID * 8);
    float*   pa   = (float*)alloc((size_t)HID * 4);
    float*   pb   = (float*)alloc((size_t)HID * 4);

    // ---- prep ----
    hipMemsetAsync(W4p, 0, (size_t)16 * HID, stream);
    k_bin_f32_to_i8<<<(HID * IND / 16 + 255) / 256, 256, 0, stream>>>(w1, W1, HID * IND / 16);
    k_bin_f32_to_i8<<<(HID * HID / 16 + 255) / 256, 256, 0, stream>>>(w2, W2, HID * HID / 16);
    k_bin_f32_to_i8<<<(HID * HID / 16 + 255) / 256, 256, 0, stream>>>(w3, W3, HID * HID / 16);
    k_bin_f32_to_i8<<<(10 * HID / 16 + 255) / 256, 256, 0, stream>>>(w4, W4p, 10 * HID / 16);
    k_bin_x<<<B * 48 / 256, 256, 0, stream>>>(x, Abuf);

    const int nbx = HID / 256, nby = B / 256;   // 16 x 64 = 1024 blocks (%8==0)

    // ---- layer 1 ----
    hipMemsetAsync(gsum, 0, HID * 12, stream);
    k_gemm256<<<nbx * nby, 512, 0, stream>>>(Abuf, W1, C, gsum, gsq, HID, IND, nbx);
    k_finalize<<<HID / 128, 128, 0, stream>>>(gsum, gsq, g1, b1, pa, pb, B, HID, HID);
    k_bnbin<<<B * HID / 16 / 256, 256, 0, stream>>>(C, pa, pb, Abuf, B * HID / 16, HID - 1);

    // ---- layer 2 ----
    hipMemsetAsync(gsum, 0, HID * 12, stream);
    k_gemm256<<<nbx * nby, 512, 0, stream>>>(Abuf, W2, C, gsum, gsq, HID, HID, nbx);
    k_finalize<<<HID / 128, 128, 0, stream>>>(gsum, gsq, g2, b2, pa, pb, B, HID, HID);
    k_bnbin<<<B * HID / 16 / 256, 256, 0, stream>>>(C, pa, pb, Abuf, B * HID / 16, HID - 1);

    // ---- layer 3 ----
    hipMemsetAsync(gsum, 0, HID * 12, stream);
    k_gemm256<<<nbx * nby, 512, 0, stream>>>(Abuf, W3, C, gsum, gsq, HID, HID, nbx);
    k_finalize<<<HID / 128, 128, 0, stream>>>(gsum, gsq, g3, b3, pa, pb, B, HID, HID);
    k_bnbin<<<B * HID / 16 / 256, 256, 0, stream>>>(C, pa, pb, Abuf, B * HID / 16, HID - 1);

    // ---- layer 4 (split-K, int32 atomics) ----
    hipMemsetAsync(C4, 0, (size_t)B * 16 * 4, stream);
    k_gemm4<<<dim3(B / 128, 8), 256, 0, stream>>>(Abuf, W4p, C4, HID);
    hipMemsetAsync(gsum, 0, HID * 12, stream);
    k_colstats4<<<16, 256, 0, stream>>>(C4, B, gsum, gsq);
    k_finalize<<<1, 128, 0, stream>>>(gsum, gsq, g4, b4, pa, pb, B, 10, 16);
    k_logsoftmax<<<B / 256, 256, 0, stream>>>(C4, pa, pb, out, B);
}